// Round 1
// 225.467 us; speedup vs baseline: 1.0792x; 1.0792x over previous
//
#include <hip/hip_runtime.h>

// Problem constants
#define NNODES  50000
#define D       128
#define E       32
#define NMP     3
#define DEG     32
#define NEDGE   200000
#define B       1024
#define NC      8
#define S       16

#define RPM      17408   // rows per mp in L0 row space (16384 level-1 + 1024 level-0)
#define NKT      9       // K tiles of 32 (K=288)
#define WSTRIDE  36864   // ushorts per (mp,lay) feat-weight block: 9*4*128*8
#define WESTRIDE 9216    // ushorts per mp edge-weight block: 9*4*32*8

#define CONV_TASKS (1600000 + 6 * WSTRIDE + 3 * WESTRIDE)   // 1,848,832
#define TOT_TASKS  (CONV_TASKS + 3 * RPM)                    // 1,901,056 = 7426*256

typedef float f4 __attribute__((ext_vector_type(4)));
typedef short bh8 __attribute__((ext_vector_type(8)));   // 8 bf16 in 4 VGPRs
typedef unsigned int uv4 __attribute__((ext_vector_type(4)));
typedef unsigned int uv2 __attribute__((ext_vector_type(2)));
typedef int iv4 __attribute__((ext_vector_type(4)));
typedef int iv2 __attribute__((ext_vector_type(2)));

static __device__ __forceinline__ unsigned short f2bf(float f) {
    unsigned int u = __float_as_uint(f);
    u = u + 0x7FFFu + ((u >> 16) & 1u);   // RN-even
    return (unsigned short)(u >> 16);
}
static __device__ __forceinline__ float bf2f(unsigned short h) {
    return __uint_as_float(((unsigned int)h) << 16);
}

// ---------- fused one-shot conversion + level-1 sampling ----------
// B-fragment order: dst[((kt*4+q)*N + n)*8 + j] = W[k = kt*32+q*8+j][n]
__global__ __launch_bounds__(256) void convsamp_k(
    const float* __restrict__ feats, const float* __restrict__ Ws,
    const float* __restrict__ Wn, const float* __restrict__ We,
    const int* __restrict__ ids, const int* __restrict__ adjn,
    const int* __restrict__ adje,
    unsigned short* __restrict__ fb, unsigned short* __restrict__ WT0,
    unsigned short* __restrict__ WTe, int* __restrict__ gx, int* __restrict__ eid1)
{
    int i = blockIdx.x * 256 + threadIdx.x;
    if (i < 1600000) {                          // feats: 50000*128/4 float4 tasks
        float4 v = ((const float4*)feats)[i];
        unsigned int p0 = (unsigned int)f2bf(v.x) | ((unsigned int)f2bf(v.y) << 16);
        unsigned int p1 = (unsigned int)f2bf(v.z) | ((unsigned int)f2bf(v.w) << 16);
        ((uint2*)fb)[i] = make_uint2(p0, p1);
    } else if (i < 1600000 + 6 * WSTRIDE) {     // feat weights: [mp][lay] K=288 (Ws||Wn), N=128
        int i2 = i - 1600000;
        int ml = i2 / WSTRIDE, e = i2 % WSTRIDE;
        int j = e & 7, t1 = e >> 3;
        int n = t1 & 127, t2 = t1 >> 7;
        int q = t2 & 3, kt = t2 >> 2;
        int k = kt * 32 + q * 8 + j;
        float v = (k < 128) ? Ws[((size_t)ml * 128 + k) * 128 + n]
                            : Wn[((size_t)ml * 160 + (k - 128)) * 128 + n];
        WT0[(size_t)ml * WSTRIDE + e] = f2bf(v);
    } else if (i < CONV_TASKS) {                // edge weights: [mp][lay0] K=288,N=32
        int i3 = i - 1600000 - 6 * WSTRIDE;
        int mp = i3 / WESTRIDE, e = i3 % WESTRIDE;
        int j = e & 7, t1 = e >> 3;
        int n = t1 & 31, t2 = t1 >> 5;
        int q = t2 & 3, kt = t2 >> 2;
        int k = kt * 32 + q * 8 + j;
        float v = We[(((size_t)mp * 2) * 288 + k) * 32 + n];
        WTe[(size_t)mp * WESTRIDE + e] = f2bf(v);
    } else if (i < TOT_TASKS) {                 // sampling: 3*RPM tasks
        int i4 = i - CONV_TASKS;
        int mp = i4 / RPM, r = i4 % RPM;
        if (r < 16384) {
            int node = ids[r >> 4];
            gx[mp * RPM + r]     = adjn[((size_t)mp * NNODES + node) * DEG + (r & 15)];
            eid1[mp * 16384 + r] = adje[((size_t)mp * NNODES + node) * DEG + (r & 15)];
        } else {
            gx[mp * RPM + r] = ids[r - 16384];
        }
    }
}

// ---------- fused gather-mean + layer-0 MFMA GEMM -> fout [mp][RPM][128] bf16 ----------
// Uniform row recipe (both levels): src = gx[mp][r]; neighbors = adjn[mp][src][:16];
// edges = adje[mp][src][:16]; self = fb[src].
// Phase A: per-lane vector index loads (no readfirstlane / scalar chase), then
// 16-lane-group dwordx4 gathers: one instruction = 4 neighbor rows (1 KB).
// 9 VMEM instrs per row vs ~25 before; dependence depth 2; means via shfl trees.
__global__ __launch_bounds__(256, 4) void aggfeat_k(
    const unsigned short* __restrict__ fb, const float* __restrict__ edge_emb,
    const int* __restrict__ adjn, const int* __restrict__ adje,
    const int* __restrict__ gx, const int* __restrict__ eid1,
    const unsigned short* __restrict__ WT0,
    unsigned short* __restrict__ fout)
{
    __shared__ unsigned short Asm[16][136];   // self feats (128 used)
    __shared__ unsigned short Nsm[16][168];   // nin rows (160 used)
    const int mp = blockIdx.y;
    const int w = threadIdx.x >> 6, l = threadIdx.x & 63;
    const int r0 = blockIdx.x * 16;
    const unsigned int* fb32 = (const unsigned int*)fb;
    const float* ee = edge_emb + (size_t)mp * NEDGE * E;
    const float inv = 1.0f / (float)S;
    const int g = l >> 4, c = l & 15;         // neighbor gather: group g covers nbrs 4g..4g+3
    const int d8 = l & 7;                     // edge gather: 8 lanes per edge row

    // ---- phase A: wave w owns rows w*4 .. w*4+3 ----
    int srcs[4];
#pragma unroll
    for (int rr = 0; rr < 4; ++rr)
        srcs[rr] = gx[mp * RPM + r0 + w * 4 + rr];

    iv4 nIdx[4]; iv2 eIdx[4]; unsigned int selfu[4];
#pragma unroll
    for (int rr = 0; rr < 4; ++rr) {
        const int* nb = adjn + ((size_t)mp * NNODES + srcs[rr]) * DEG;
        const int* eb = adje + ((size_t)mp * NNODES + srcs[rr]) * DEG;
        nIdx[rr] = *(const iv4*)(nb + 4 * g);          // nbrs 4g..4g+3 of row rr
        eIdx[rr] = *(const iv2*)(eb + 2 * (l >> 3));   // edges 2h, 2h+1
        selfu[rr] = fb32[(size_t)srcs[rr] * 64 + l];
    }

#pragma unroll
    for (int pp = 0; pp < 2; ++pp) {
        const int lra = w * 4 + 2 * pp, lrb = lra + 1;
        const int ia = 2 * pp, ib = 2 * pp + 1;

        uv4 gA[4], gB[4];
#pragma unroll
        for (int p = 0; p < 4; ++p)
            gA[p] = *(const uv4*)(fb32 + (size_t)nIdx[ia][p] * 64 + c * 4);
#pragma unroll
        for (int p = 0; p < 4; ++p)
            gB[p] = *(const uv4*)(fb32 + (size_t)nIdx[ib][p] * 64 + c * 4);
        f4 eA0 = *(const f4*)(ee + (size_t)eIdx[ia][0] * E + d8 * 4);
        f4 eA1 = *(const f4*)(ee + (size_t)eIdx[ia][1] * E + d8 * 4);
        f4 eB0 = *(const f4*)(ee + (size_t)eIdx[ib][0] * E + d8 * 4);
        f4 eB1 = *(const f4*)(ee + (size_t)eIdx[ib][1] * E + d8 * 4);

        // per-lane partial sums over this group's 4 neighbors; dims c*8 .. c*8+7
        float accA[8], accB[8];
#pragma unroll
        for (int d = 0; d < 8; ++d) { accA[d] = 0.f; accB[d] = 0.f; }
#pragma unroll
        for (int p = 0; p < 4; ++p)
#pragma unroll
            for (int qq = 0; qq < 4; ++qq) {
                unsigned int ua = gA[p][qq], ub = gB[p][qq];
                accA[2 * qq]     += __uint_as_float(ua << 16);
                accA[2 * qq + 1] += __uint_as_float(ua & 0xffff0000u);
                accB[2 * qq]     += __uint_as_float(ub << 16);
                accB[2 * qq + 1] += __uint_as_float(ub & 0xffff0000u);
            }
        // reduce across the 4 lane-groups (same dim slice at l^16, l^32)
#pragma unroll
        for (int d = 0; d < 8; ++d) {
            accA[d] += __shfl_xor(accA[d], 16);
            accA[d] += __shfl_xor(accA[d], 32);
            accB[d] += __shfl_xor(accB[d], 16);
            accB[d] += __shfl_xor(accB[d], 32);
        }
        // edge dims d8*4 .. d8*4+3, reduce across 8 edge-groups
        float feA[4], feB[4];
#pragma unroll
        for (int qq = 0; qq < 4; ++qq) {
            feA[qq] = eA0[qq] + eA1[qq];
            feB[qq] = eB0[qq] + eB1[qq];
            feA[qq] += __shfl_xor(feA[qq], 8);
            feA[qq] += __shfl_xor(feA[qq], 16);
            feA[qq] += __shfl_xor(feA[qq], 32);
            feB[qq] += __shfl_xor(feB[qq], 8);
            feB[qq] += __shfl_xor(feB[qq], 16);
            feB[qq] += __shfl_xor(feB[qq], 32);
        }

        ((unsigned int*)&Asm[lra][0])[l] = selfu[ia];
        ((unsigned int*)&Asm[lrb][0])[l] = selfu[ib];
        if (g == 0) {
            uv4 oa, ob;
#pragma unroll
            for (int qq = 0; qq < 4; ++qq) {
                oa[qq] = (unsigned int)f2bf(accA[2 * qq] * inv)
                       | ((unsigned int)f2bf(accA[2 * qq + 1] * inv) << 16);
                ob[qq] = (unsigned int)f2bf(accB[2 * qq] * inv)
                       | ((unsigned int)f2bf(accB[2 * qq + 1] * inv) << 16);
            }
            *(uv4*)&Nsm[lra][c * 8] = oa;
            *(uv4*)&Nsm[lrb][c * 8] = ob;
        }
        if (l < 8) {
            uv2 oa, ob;
            oa[0] = (unsigned int)f2bf(feA[0] * inv) | ((unsigned int)f2bf(feA[1] * inv) << 16);
            oa[1] = (unsigned int)f2bf(feA[2] * inv) | ((unsigned int)f2bf(feA[3] * inv) << 16);
            ob[0] = (unsigned int)f2bf(feB[0] * inv) | ((unsigned int)f2bf(feB[1] * inv) << 16);
            ob[1] = (unsigned int)f2bf(feB[2] * inv) | ((unsigned int)f2bf(feB[3] * inv) << 16);
            *(uv2*)&Nsm[lra][128 + d8 * 4] = oa;
            *(uv2*)&Nsm[lrb][128 + d8 * 4] = ob;
        }
    }
    __syncthreads();

    // ---- phase B: wave w computes n-tiles {2w, 2w+1} of the single m-tile ----
    const int q = l >> 4, lm = l & 15;
    const unsigned short* wb = WT0 + (size_t)mp * 2 * WSTRIDE;   // layer 0

    f4 acc[2];
    acc[0] = (f4){0.f, 0.f, 0.f, 0.f};
    acc[1] = (f4){0.f, 0.f, 0.f, 0.f};

#pragma unroll
    for (int kt = 0; kt < NKT; ++kt) {
        const int k0 = kt * 32 + q * 8;
        bh8 a = (k0 < 128) ? *(const bh8*)&Asm[lm][k0]
                           : *(const bh8*)&Nsm[lm][k0 - 128];
        const unsigned short* wrow = wb + ((size_t)(kt * 4 + q) * 128 + lm) * 8;
#pragma unroll
        for (int ntl = 0; ntl < 2; ++ntl) {
            bh8 bf = *(const bh8*)(wrow + (w * 2 + ntl) * 16 * 8);
            acc[ntl] = __builtin_amdgcn_mfma_f32_16x16x32_bf16(a, bf, acc[ntl], 0, 0, 0);
        }
    }

#pragma unroll
    for (int ntl = 0; ntl < 2; ++ntl)
#pragma unroll
        for (int rr = 0; rr < 4; ++rr) {
            int row = r0 + q * 4 + rr;             // C/D: col=lane&15, row=quad*4+reg
            int col = (w * 2 + ntl) * 16 + lm;
            fout[((size_t)mp * RPM + row) * 128 + col] = f2bf(fmaxf(acc[ntl][rr], 0.f));
        }
}

// ---------- fused edge GEMM + layer-1 mean -> agg1 [mp][B][160] bf16 ----------
// One m-tile (= one segment) per wave; 768 blocks for latency hiding.
__global__ __launch_bounds__(256) void edgeagg_k(
    const unsigned short* __restrict__ fout, const float* __restrict__ edge_emb,
    const int* __restrict__ eid1, const unsigned short* __restrict__ WTe,
    unsigned short* __restrict__ agg1)
{
    const int mp = blockIdx.y;
    const int w = threadIdx.x >> 6, l = threadIdx.x & 63;
    const int q = l >> 4, lm = l & 15;
    const int m0 = blockIdx.x * 64 + w * 16;           // wave: 1 m-tile = 1 segment
    const unsigned short* we = WTe + (size_t)mp * WESTRIDE;
    const unsigned short* f1base = fout + (size_t)mp * RPM * 128;
    const unsigned short* f0base = fout + ((size_t)mp * RPM + 16384) * 128;
    const float* ee = edge_emb + (size_t)mp * NEDGE * E;
    const float inv = 1.0f / (float)S;

    const int row = m0 + lm;
    const unsigned short* a1p = f1base + (size_t)row * 128;
    const unsigned short* a0p = f0base + (size_t)(row >> 4) * 128;
    const int eidL = eid1[mp * 16384 + row];

    f4 acc[2];
    acc[0] = (f4){0.f, 0.f, 0.f, 0.f};
    acc[1] = (f4){0.f, 0.f, 0.f, 0.f};

#pragma unroll
    for (int kt = 0; kt < NKT; ++kt) {
        const int k0 = kt * 32 + q * 8;
        bh8 a;
        if (kt < 4) {
            a = *(const bh8*)(a0p + k0);
        } else if (kt < 8) {
            a = *(const bh8*)(a1p + (k0 - 128));
        } else {
            const float* ep = ee + (size_t)eidL * E + q * 8;
            float4 v0 = *(const float4*)ep;
            float4 v1 = *(const float4*)(ep + 4);
            bh8 tv;
            tv[0] = (short)f2bf(v0.x); tv[1] = (short)f2bf(v0.y);
            tv[2] = (short)f2bf(v0.z); tv[3] = (short)f2bf(v0.w);
            tv[4] = (short)f2bf(v1.x); tv[5] = (short)f2bf(v1.y);
            tv[6] = (short)f2bf(v1.z); tv[7] = (short)f2bf(v1.w);
            a = tv;
        }
        const unsigned short* wrow = we + ((size_t)(kt * 4 + q) * 32 + lm) * 8;
        bh8 b0 = *(const bh8*)(wrow);
        bh8 b1 = *(const bh8*)(wrow + 16 * 8);
        acc[0] = __builtin_amdgcn_mfma_f32_16x16x32_bf16(a, b0, acc[0], 0, 0, 0);
        acc[1] = __builtin_amdgcn_mfma_f32_16x16x32_bf16(a, b1, acc[1], 0, 0, 0);
    }

    // edge part of agg1: mean over the 16 rows of this segment
    const int seg = m0 >> 4;
#pragma unroll
    for (int nt = 0; nt < 2; ++nt) {
        float ps = 0.f;
#pragma unroll
        for (int rr = 0; rr < 4; ++rr) ps += fmaxf(acc[nt][rr], 0.f);
        ps += __shfl_xor(ps, 16);
        ps += __shfl_xor(ps, 32);                   // sum over quads -> full column sum
        if (l < 16)
            agg1[((size_t)mp * B + seg) * 160 + 128 + nt * 16 + lm] = f2bf(ps * inv);
    }

    // f1 part of agg1: mean of fout level-1 rows for this wave's segment
    {
        const unsigned short* fr = f1base + (size_t)seg * 16 * 128;
        float s0 = 0.f, s1 = 0.f;
#pragma unroll
        for (int j = 0; j < S; ++j) {
            unsigned int u = ((const unsigned int*)(fr + j * 128))[l];
            s0 += bf2f((unsigned short)(u & 0xFFFF));
            s1 += bf2f((unsigned short)(u >> 16));
        }
        ((unsigned int*)(agg1 + ((size_t)mp * B + seg) * 160))[l] =
            (unsigned int)f2bf(s0 * inv) | ((unsigned int)f2bf(s1 * inv) << 16);
    }
}

// ---------- fused layer-1 GEMM (all 3 mps) + attention + normalize + fc ----------
// 64 blocks x 16 rows (was 32 x 32): double the CU coverage, half the per-block
// serial chain. Tasks: (mp, n-half); wave w does task w, waves 0,1 also 4+w.
__global__ __launch_bounds__(256) void feat1fin_k(
    const unsigned short* __restrict__ fout, const unsigned short* __restrict__ agg1,
    const unsigned short* __restrict__ WT0,
    const float* __restrict__ attn, const float* __restrict__ fcw,
    const float* __restrict__ fcb, float* __restrict__ out)
{
    __shared__ float sbuf[NMP][16][132];                // +4 pad: conflict-free stores
    const int w = threadIdx.x >> 6, l = threadIdx.x & 63;
    const int q = l >> 4, lm = l & 15;
    const int m0 = blockIdx.x * 16;

    for (int task = w; task < 6; task += 4) {
        const int mp = task >> 1, nh = task & 1;        // nh: which 4 n-tiles
        const int row = m0 + lm;                        // < 1024
        const unsigned short* ap = fout + ((size_t)mp * RPM + 16384 + row) * 128;
        const unsigned short* np = agg1 + ((size_t)mp * B + row) * 160;
        const unsigned short* wb = WT0 + ((size_t)mp * 2 + 1) * WSTRIDE;

        f4 acc[4];
#pragma unroll
        for (int nt = 0; nt < 4; ++nt) acc[nt] = (f4){0.f, 0.f, 0.f, 0.f};
#pragma unroll
        for (int kt = 0; kt < NKT; ++kt) {
            const int k0 = kt * 32 + q * 8;
            bh8 a = (k0 < 128) ? *(const bh8*)(ap + k0) : *(const bh8*)(np + (k0 - 128));
            const unsigned short* wrow = wb + ((size_t)(kt * 4 + q) * 128 + lm) * 8;
#pragma unroll
            for (int nt = 0; nt < 4; ++nt) {
                bh8 bf = *(const bh8*)(wrow + (nh * 4 + nt) * 16 * 8);
                acc[nt] = __builtin_amdgcn_mfma_f32_16x16x32_bf16(a, bf, acc[nt], 0, 0, 0);
            }
        }
#pragma unroll
        for (int nt = 0; nt < 4; ++nt)
#pragma unroll
            for (int rr = 0; rr < 4; ++rr)
                sbuf[mp][q * 4 + rr][(nh * 4 + nt) * 16 + lm] = fmaxf(acc[nt][rr], 0.f);
    }
    __syncthreads();

    // finalize: 8 threads per row, 16 dims each; rows 0..15 -> threads 0..127
    if (threadIdx.x < 128) {
        const int row = threadIdx.x >> 3;               // [0,16)
        const int j = threadIdx.x & 7;
        const int d0 = j * 16;
        float sc[NMP];
#pragma unroll
        for (int mp = 0; mp < NMP; ++mp) {
            float p = 0.f;
#pragma unroll
            for (int d = 0; d < 16; ++d) p += sbuf[mp][row][d0 + d] * attn[d0 + d];
            p += __shfl_xor(p, 1); p += __shfl_xor(p, 2); p += __shfl_xor(p, 4);
            sc[mp] = tanhf(p);
        }
        float mx = fmaxf(sc[0], fmaxf(sc[1], sc[2]));
        float e0 = expf(sc[0] - mx), e1 = expf(sc[1] - mx), e2 = expf(sc[2] - mx);
        float isum = 1.f / (e0 + e1 + e2);
        float b0 = e0 * isum, b1 = e1 * isum, b2 = e2 * isum;

        float emb[16];
        float nn = 0.f;
#pragma unroll
        for (int d = 0; d < 16; ++d) {
            float v = b0 * sbuf[0][row][d0 + d] + b1 * sbuf[1][row][d0 + d]
                    + b2 * sbuf[2][row][d0 + d];
            emb[d] = v;
            nn += v * v;
        }
        nn += __shfl_xor(nn, 1); nn += __shfl_xor(nn, 2); nn += __shfl_xor(nn, 4);
        float innorm = 1.f / fmaxf(sqrtf(nn), 1e-12f);
#pragma unroll
        for (int d = 0; d < 16; ++d) emb[d] *= innorm;

#pragma unroll
        for (int cc = 0; cc < NC; ++cc) {
            float p = 0.f;
#pragma unroll
            for (int d = 0; d < 16; ++d) p += emb[d] * fcw[(d0 + d) * NC + cc];
            p += __shfl_xor(p, 1); p += __shfl_xor(p, 2); p += __shfl_xor(p, 4);
            if (j == cc) out[(size_t)(m0 + row) * NC + cc] = p + fcb[cc];
        }
    }
}

extern "C" void kernel_launch(void* const* d_in, const int* in_sizes, int n_in,
                              void* d_out, int out_size, void* d_ws, size_t ws_size,
                              hipStream_t stream) {
    const int* ids        = (const int*)d_in[0];
    const float* feats    = (const float*)d_in[1];
    const float* edge_emb = (const float*)d_in[2];
    const int* adjn       = (const int*)d_in[3];
    const int* adje       = (const int*)d_in[4];
    const float* Ws       = (const float*)d_in[5];
    const float* Wn       = (const float*)d_in[6];
    const float* We       = (const float*)d_in[7];
    const float* attn     = (const float*)d_in[8];
    const float* fcw      = (const float*)d_in[9];
    const float* fcb      = (const float*)d_in[10];
    float* out = (float*)d_out;

    // workspace layout (~28 MB; all regions fully written before read each call)
    char* p = (char*)d_ws;
    unsigned short* WT0 = (unsigned short*)p; p += (size_t)6 * WSTRIDE * 2;
    unsigned short* WTe = (unsigned short*)p; p += (size_t)3 * WESTRIDE * 2;
    unsigned short* fb  = (unsigned short*)p; p += (size_t)NNODES * 128 * 2;
    int* gx   = (int*)p;                      p += (size_t)3 * RPM * 4;
    int* eid1 = (int*)p;                      p += (size_t)3 * 16384 * 4;
    unsigned short* fout = (unsigned short*)p; p += (size_t)3 * RPM * 128 * 2;
    unsigned short* agg1 = (unsigned short*)p; p += (size_t)3 * B * 160 * 2;

    convsamp_k<<<TOT_TASKS / 256, 256, 0, stream>>>(feats, Ws, Wn, We, ids, adjn, adje,
                                                    fb, WT0, WTe, gx, eid1);
    aggfeat_k<<<dim3(RPM / 16, 3), 256, 0, stream>>>(fb, edge_emb, adjn, adje, gx, eid1,
                                                     WT0, fout);
    edgeagg_k<<<dim3(256, 3), 256, 0, stream>>>(fout, edge_emb, eid1, WTe, agg1);
    feat1fin_k<<<64, 256, 0, stream>>>(fout, agg1, WT0, attn, fcw, fcb, out);
}

// Round 2
// 224.823 us; speedup vs baseline: 1.0823x; 1.0029x over previous
//
#include <hip/hip_runtime.h>

// Problem constants
#define NNODES  50000
#define D       128
#define E       32
#define NMP     3
#define DEG     32
#define NEDGE   200000
#define B       1024
#define NC      8
#define S       16

#define RPM      17408   // rows per mp in L0 row space (16384 level-1 + 1024 level-0)
#define NKT      9       // K tiles of 32 (K=288)
#define WSTRIDE  36864   // ushorts per (mp,lay) feat-weight block: 9*4*128*8
#define WESTRIDE 9216    // ushorts per mp edge-weight block: 9*4*32*8

#define CONV_TASKS (1600000 + 6 * WSTRIDE + 3 * WESTRIDE)   // 1,848,832
#define TOT_TASKS  (CONV_TASKS + 3 * RPM)                    // 1,901,056 = 7426*256

typedef float f4 __attribute__((ext_vector_type(4)));
typedef short bh8 __attribute__((ext_vector_type(8)));   // 8 bf16 in 4 VGPRs
typedef unsigned int uv4 __attribute__((ext_vector_type(4)));
typedef unsigned int uv2 __attribute__((ext_vector_type(2)));
typedef int iv4 __attribute__((ext_vector_type(4)));
typedef int iv2 __attribute__((ext_vector_type(2)));

static __device__ __forceinline__ unsigned short f2bf(float f) {
    unsigned int u = __float_as_uint(f);
    u = u + 0x7FFFu + ((u >> 16) & 1u);   // RN-even
    return (unsigned short)(u >> 16);
}
static __device__ __forceinline__ float bf2f(unsigned short h) {
    return __uint_as_float(((unsigned int)h) << 16);
}

// ---------- fused one-shot conversion + level-1 sampling ----------
// B-fragment order: dst[((kt*4+q)*N + n)*8 + j] = W[k = kt*32+q*8+j][n]
__global__ __launch_bounds__(256) void convsamp_k(
    const float* __restrict__ feats, const float* __restrict__ Ws,
    const float* __restrict__ Wn, const float* __restrict__ We,
    const int* __restrict__ ids, const int* __restrict__ adjn,
    const int* __restrict__ adje,
    unsigned short* __restrict__ fb, unsigned short* __restrict__ WT0,
    unsigned short* __restrict__ WTe, int* __restrict__ gx, int* __restrict__ eid1)
{
    int i = blockIdx.x * 256 + threadIdx.x;
    if (i < 1600000) {                          // feats: 50000*128/4 float4 tasks
        float4 v = ((const float4*)feats)[i];
        unsigned int p0 = (unsigned int)f2bf(v.x) | ((unsigned int)f2bf(v.y) << 16);
        unsigned int p1 = (unsigned int)f2bf(v.z) | ((unsigned int)f2bf(v.w) << 16);
        ((uint2*)fb)[i] = make_uint2(p0, p1);
    } else if (i < 1600000 + 6 * WSTRIDE) {     // feat weights: [mp][lay] K=288 (Ws||Wn), N=128
        int i2 = i - 1600000;
        int ml = i2 / WSTRIDE, e = i2 % WSTRIDE;
        int j = e & 7, t1 = e >> 3;
        int n = t1 & 127, t2 = t1 >> 7;
        int q = t2 & 3, kt = t2 >> 2;
        int k = kt * 32 + q * 8 + j;
        float v = (k < 128) ? Ws[((size_t)ml * 128 + k) * 128 + n]
                            : Wn[((size_t)ml * 160 + (k - 128)) * 128 + n];
        WT0[(size_t)ml * WSTRIDE + e] = f2bf(v);
    } else if (i < CONV_TASKS) {                // edge weights: [mp][lay0] K=288,N=32
        int i3 = i - 1600000 - 6 * WSTRIDE;
        int mp = i3 / WESTRIDE, e = i3 % WESTRIDE;
        int j = e & 7, t1 = e >> 3;
        int n = t1 & 31, t2 = t1 >> 5;
        int q = t2 & 3, kt = t2 >> 2;
        int k = kt * 32 + q * 8 + j;
        float v = We[(((size_t)mp * 2) * 288 + k) * 32 + n];
        WTe[(size_t)mp * WESTRIDE + e] = f2bf(v);
    } else if (i < TOT_TASKS) {                 // sampling: 3*RPM tasks
        int i4 = i - CONV_TASKS;
        int mp = i4 / RPM, r = i4 % RPM;
        if (r < 16384) {
            int node = ids[r >> 4];
            gx[mp * RPM + r]     = adjn[((size_t)mp * NNODES + node) * DEG + (r & 15)];
            eid1[mp * 16384 + r] = adje[((size_t)mp * NNODES + node) * DEG + (r & 15)];
        } else {
            gx[mp * RPM + r] = ids[r - 16384];
        }
    }
}

// ---------- fused gather-mean + layer-0 MFMA GEMM -> fout [mp][RPM][128] bf16 ----------
// Phase A: all 48 gather loads for the wave's 4 rows issued BEFORE an
// asm-"memory" compiler fence, so the scheduler cannot sink them into the
// consumption chain (round-1 failure mode: VGPR stayed 56, loads serialized).
// launch_bounds(256,3) caps VGPRs at ~168: room for ~96 landing regs, no spill.
__global__ __launch_bounds__(256, 3) void aggfeat_k(
    const unsigned short* __restrict__ fb, const float* __restrict__ edge_emb,
    const int* __restrict__ adjn, const int* __restrict__ adje,
    const int* __restrict__ gx, const int* __restrict__ eid1,
    const unsigned short* __restrict__ WT0,
    unsigned short* __restrict__ fout)
{
    __shared__ unsigned short Asm[16][136];   // self feats (128 used)
    __shared__ unsigned short Nsm[16][168];   // nin rows (160 used)
    const int mp = blockIdx.y;
    const int w = threadIdx.x >> 6, l = threadIdx.x & 63;
    const int r0 = blockIdx.x * 16;
    const unsigned int* fb32 = (const unsigned int*)fb;
    const float* ee = edge_emb + (size_t)mp * NEDGE * E;
    const float inv = 1.0f / (float)S;
    const int g = l >> 4, c = l & 15;         // neighbor gather: group g covers nbrs 4g..4g+3
    const int d8 = l & 7;                     // edge gather: 8 lanes per edge row

    // ---- phase A: wave w owns rows w*4 .. w*4+3 ----
    iv4 srcv = *(const iv4*)(gx + mp * RPM + r0 + w * 4);

    iv4 nIdx[4]; iv2 eIdx[4]; unsigned int selfu[4];
#pragma unroll
    for (int rr = 0; rr < 4; ++rr) {
        const int src = srcv[rr];
        nIdx[rr]  = *(const iv4*)(adjn + ((size_t)mp * NNODES + src) * DEG + 4 * g);
        eIdx[rr]  = *(const iv2*)(adje + ((size_t)mp * NNODES + src) * DEG + 2 * (l >> 3));
        selfu[rr] = fb32[(size_t)src * 64 + l];
    }

    // issue ALL gathers for all 4 rows (24 VMEM, ~96 landing VGPRs)
    uv4 gN[4][4];
    f4  gE[4][2];
#pragma unroll
    for (int rr = 0; rr < 4; ++rr) {
#pragma unroll
        for (int p = 0; p < 4; ++p)
            gN[rr][p] = *(const uv4*)(fb32 + (size_t)nIdx[rr][p] * 64 + c * 4);
        gE[rr][0] = *(const f4*)(ee + (size_t)eIdx[rr][0] * E + d8 * 4);
        gE[rr][1] = *(const f4*)(ee + (size_t)eIdx[rr][1] * E + d8 * 4);
    }
    asm volatile("" ::: "memory");   // hard fence: no load may sink past here

#pragma unroll
    for (int rr = 0; rr < 4; ++rr) {
        const int lr = w * 4 + rr;
        float acc[8];
#pragma unroll
        for (int d = 0; d < 8; ++d) acc[d] = 0.f;
#pragma unroll
        for (int p = 0; p < 4; ++p)
#pragma unroll
            for (int qq = 0; qq < 4; ++qq) {
                unsigned int u = gN[rr][p][qq];
                acc[2 * qq]     += __uint_as_float(u << 16);
                acc[2 * qq + 1] += __uint_as_float(u & 0xffff0000u);
            }
#pragma unroll
        for (int d = 0; d < 8; ++d) {
            acc[d] += __shfl_xor(acc[d], 16);
            acc[d] += __shfl_xor(acc[d], 32);
        }
        float fe[4];
#pragma unroll
        for (int qq = 0; qq < 4; ++qq) {
            fe[qq] = gE[rr][0][qq] + gE[rr][1][qq];
            fe[qq] += __shfl_xor(fe[qq], 8);
            fe[qq] += __shfl_xor(fe[qq], 16);
            fe[qq] += __shfl_xor(fe[qq], 32);
        }

        ((unsigned int*)&Asm[lr][0])[l] = selfu[rr];
        if (g == 0) {
            uv4 o;
#pragma unroll
            for (int qq = 0; qq < 4; ++qq)
                o[qq] = (unsigned int)f2bf(acc[2 * qq] * inv)
                      | ((unsigned int)f2bf(acc[2 * qq + 1] * inv) << 16);
            *(uv4*)&Nsm[lr][c * 8] = o;
        }
        if (l < 8) {
            uv2 o;
            o[0] = (unsigned int)f2bf(fe[0] * inv) | ((unsigned int)f2bf(fe[1] * inv) << 16);
            o[1] = (unsigned int)f2bf(fe[2] * inv) | ((unsigned int)f2bf(fe[3] * inv) << 16);
            *(uv2*)&Nsm[lr][128 + d8 * 4] = o;
        }
    }
    __syncthreads();

    // ---- phase B: wave w computes n-tiles {2w, 2w+1} of the single m-tile ----
    const int q = l >> 4, lm = l & 15;
    const unsigned short* wb = WT0 + (size_t)mp * 2 * WSTRIDE;   // layer 0

    f4 acc[2];
    acc[0] = (f4){0.f, 0.f, 0.f, 0.f};
    acc[1] = (f4){0.f, 0.f, 0.f, 0.f};

#pragma unroll
    for (int kt = 0; kt < NKT; ++kt) {
        const int k0 = kt * 32 + q * 8;
        bh8 a = (k0 < 128) ? *(const bh8*)&Asm[lm][k0]
                           : *(const bh8*)&Nsm[lm][k0 - 128];
        const unsigned short* wrow = wb + ((size_t)(kt * 4 + q) * 128 + lm) * 8;
#pragma unroll
        for (int ntl = 0; ntl < 2; ++ntl) {
            bh8 bf = *(const bh8*)(wrow + (w * 2 + ntl) * 16 * 8);
            acc[ntl] = __builtin_amdgcn_mfma_f32_16x16x32_bf16(a, bf, acc[ntl], 0, 0, 0);
        }
    }

#pragma unroll
    for (int ntl = 0; ntl < 2; ++ntl)
#pragma unroll
        for (int rr = 0; rr < 4; ++rr) {
            int row = r0 + q * 4 + rr;             // C/D: col=lane&15, row=quad*4+reg
            int col = (w * 2 + ntl) * 16 + lm;
            fout[((size_t)mp * RPM + row) * 128 + col] = f2bf(fmaxf(acc[ntl][rr], 0.f));
        }
}

// ---------- fused edge GEMM + layer-1 mean + layer-1 GEMM -> femb [mp][B][128] f32 ----------
// Wave w owns segment seg = blockIdx.x*4 + w end-to-end: edge GEMM + f1 mean
// give the full agg1 row in-register; block stages its 4 rows [f0||f1mean||edge]
// into LDS and runs a 4-valid-row MFMA m-tile (rows 4-15 zero; MFMA util is 2%,
// waste is free). Kills the launch-starved feat1fin GEMM + the agg1 round-trip.
__global__ __launch_bounds__(256) void edgeagg_k(
    const unsigned short* __restrict__ fout, const float* __restrict__ edge_emb,
    const int* __restrict__ eid1, const unsigned short* __restrict__ WTe,
    const unsigned short* __restrict__ WT0,
    float* __restrict__ femb)
{
    __shared__ unsigned short As2[4][304];             // 288 used; 608B rows (16B-aligned)
    const int mp = blockIdx.y;
    const int w = threadIdx.x >> 6, l = threadIdx.x & 63;
    const int q = l >> 4, lm = l & 15;
    const int m0 = blockIdx.x * 64 + w * 16;           // wave: 1 m-tile = 1 segment
    const unsigned short* we = WTe + (size_t)mp * WESTRIDE;
    const unsigned short* f1base = fout + (size_t)mp * RPM * 128;
    const unsigned short* f0base = fout + ((size_t)mp * RPM + 16384) * 128;
    const float* ee = edge_emb + (size_t)mp * NEDGE * E;
    const float inv = 1.0f / (float)S;

    const int row = m0 + lm;
    const unsigned short* a1p = f1base + (size_t)row * 128;
    const unsigned short* a0p = f0base + (size_t)(row >> 4) * 128;
    const int eidL = eid1[mp * 16384 + row];

    f4 acc[2];
    acc[0] = (f4){0.f, 0.f, 0.f, 0.f};
    acc[1] = (f4){0.f, 0.f, 0.f, 0.f};

#pragma unroll
    for (int kt = 0; kt < NKT; ++kt) {
        const int k0 = kt * 32 + q * 8;
        bh8 a;
        if (kt < 4) {
            a = *(const bh8*)(a0p + k0);
        } else if (kt < 8) {
            a = *(const bh8*)(a1p + (k0 - 128));
        } else {
            const float* ep = ee + (size_t)eidL * E + q * 8;
            float4 v0 = *(const float4*)ep;
            float4 v1 = *(const float4*)(ep + 4);
            bh8 tv;
            tv[0] = (short)f2bf(v0.x); tv[1] = (short)f2bf(v0.y);
            tv[2] = (short)f2bf(v0.z); tv[3] = (short)f2bf(v0.w);
            tv[4] = (short)f2bf(v1.x); tv[5] = (short)f2bf(v1.y);
            tv[6] = (short)f2bf(v1.z); tv[7] = (short)f2bf(v1.w);
            a = tv;
        }
        const unsigned short* wrow = we + ((size_t)(kt * 4 + q) * 32 + lm) * 8;
        bh8 b0 = *(const bh8*)(wrow);
        bh8 b1 = *(const bh8*)(wrow + 16 * 8);
        acc[0] = __builtin_amdgcn_mfma_f32_16x16x32_bf16(a, b0, acc[0], 0, 0, 0);
        acc[1] = __builtin_amdgcn_mfma_f32_16x16x32_bf16(a, b1, acc[1], 0, 0, 0);
    }

    // ---- stage this wave's agg1 row + f0 row into As2[w] ----
    // edge part: mean over the 16 rows of this segment (column sums)
#pragma unroll
    for (int nt = 0; nt < 2; ++nt) {
        float ps = 0.f;
#pragma unroll
        for (int rr = 0; rr < 4; ++rr) ps += fmaxf(acc[nt][rr], 0.f);
        ps += __shfl_xor(ps, 16);
        ps += __shfl_xor(ps, 32);                   // sum over quads -> full column sum
        if (l < 16)
            As2[w][256 + nt * 16 + lm] = f2bf(ps * inv);
    }

    // f0 row (dims 2l, 2l+1) and f1 mean
    {
        const int seg = m0 >> 4;
        unsigned int f0u = ((const unsigned int*)a0p)[l];
        ((unsigned int*)&As2[w][0])[l] = f0u;

        const unsigned short* fr = f1base + (size_t)seg * 16 * 128;
        float s0 = 0.f, s1 = 0.f;
#pragma unroll
        for (int j = 0; j < S; ++j) {
            unsigned int u = ((const unsigned int*)(fr + j * 128))[l];
            s0 += bf2f((unsigned short)(u & 0xFFFF));
            s1 += bf2f((unsigned short)(u >> 16));
        }
        ((unsigned int*)&As2[w][0])[64 + l] =
            (unsigned int)f2bf(s0 * inv) | ((unsigned int)f2bf(s1 * inv) << 16);
    }
    __syncthreads();

    // ---- fused layer-1 GEMM: 4 valid rows, 8 n-tiles over 4 waves ----
    const unsigned short* wb1 = WT0 + ((size_t)mp * 2 + 1) * WSTRIDE;
    f4 acc2[2];
    acc2[0] = (f4){0.f, 0.f, 0.f, 0.f};
    acc2[1] = (f4){0.f, 0.f, 0.f, 0.f};

#pragma unroll
    for (int kt = 0; kt < NKT; ++kt) {
        const int k0 = kt * 32 + q * 8;
        bh8 a;
        if (lm < 4) a = *(const bh8*)&As2[lm][k0];
        else        a = (bh8){0, 0, 0, 0, 0, 0, 0, 0};
        const unsigned short* wrow = wb1 + ((size_t)(kt * 4 + q) * 128 + lm) * 8;
#pragma unroll
        for (int ntl = 0; ntl < 2; ++ntl) {
            bh8 bf = *(const bh8*)(wrow + (w * 2 + ntl) * 16 * 8);
            acc2[ntl] = __builtin_amdgcn_mfma_f32_16x16x32_bf16(a, bf, acc2[ntl], 0, 0, 0);
        }
    }
    if (q == 0) {                                      // rows 0-3 live in quad 0, reg rr
#pragma unroll
        for (int ntl = 0; ntl < 2; ++ntl)
#pragma unroll
            for (int rr = 0; rr < 4; ++rr) {
                int seg = blockIdx.x * 4 + rr;
                femb[((size_t)mp * B + seg) * 128 + (w * 2 + ntl) * 16 + lm] =
                    fmaxf(acc2[ntl][rr], 0.f);
            }
    }
}

// ---------- slim finalize: attention + softmax + normalize + fc ----------
// Pure 1.5 MB-read kernel; 32 blocks x 32 rows, 8 threads/row.
__global__ __launch_bounds__(256) void fin_k(
    const float* __restrict__ femb, const float* __restrict__ attn,
    const float* __restrict__ fcw, const float* __restrict__ fcb,
    float* __restrict__ out)
{
    const int row = blockIdx.x * 32 + (threadIdx.x >> 3);
    const int j = threadIdx.x & 7;
    const int d0 = j * 16;

    float v[NMP][16];
#pragma unroll
    for (int mp = 0; mp < NMP; ++mp)
#pragma unroll
        for (int t = 0; t < 4; ++t)
            *(f4*)&v[mp][t * 4] =
                *(const f4*)&femb[((size_t)mp * B + row) * 128 + d0 + t * 4];

    float sc[NMP];
#pragma unroll
    for (int mp = 0; mp < NMP; ++mp) {
        float p = 0.f;
#pragma unroll
        for (int d = 0; d < 16; ++d) p += v[mp][d] * attn[d0 + d];
        p += __shfl_xor(p, 1); p += __shfl_xor(p, 2); p += __shfl_xor(p, 4);
        sc[mp] = tanhf(p);
    }
    float mx = fmaxf(sc[0], fmaxf(sc[1], sc[2]));
    float e0 = expf(sc[0] - mx), e1 = expf(sc[1] - mx), e2 = expf(sc[2] - mx);
    float isum = 1.f / (e0 + e1 + e2);
    float b0 = e0 * isum, b1 = e1 * isum, b2 = e2 * isum;

    float emb[16];
    float nn = 0.f;
#pragma unroll
    for (int d = 0; d < 16; ++d) {
        float vv = b0 * v[0][d] + b1 * v[1][d] + b2 * v[2][d];
        emb[d] = vv;
        nn += vv * vv;
    }
    nn += __shfl_xor(nn, 1); nn += __shfl_xor(nn, 2); nn += __shfl_xor(nn, 4);
    float innorm = 1.f / fmaxf(sqrtf(nn), 1e-12f);
#pragma unroll
    for (int d = 0; d < 16; ++d) emb[d] *= innorm;

#pragma unroll
    for (int cc = 0; cc < NC; ++cc) {
        float p = 0.f;
#pragma unroll
        for (int d = 0; d < 16; ++d) p += emb[d] * fcw[(d0 + d) * NC + cc];
        p += __shfl_xor(p, 1); p += __shfl_xor(p, 2); p += __shfl_xor(p, 4);
        if (j == cc) out[(size_t)row * NC + cc] = p + fcb[cc];
    }
}

extern "C" void kernel_launch(void* const* d_in, const int* in_sizes, int n_in,
                              void* d_out, int out_size, void* d_ws, size_t ws_size,
                              hipStream_t stream) {
    const int* ids        = (const int*)d_in[0];
    const float* feats    = (const float*)d_in[1];
    const float* edge_emb = (const float*)d_in[2];
    const int* adjn       = (const int*)d_in[3];
    const int* adje       = (const int*)d_in[4];
    const float* Ws       = (const float*)d_in[5];
    const float* Wn       = (const float*)d_in[6];
    const float* We       = (const float*)d_in[7];
    const float* attn     = (const float*)d_in[8];
    const float* fcw      = (const float*)d_in[9];
    const float* fcb      = (const float*)d_in[10];
    float* out = (float*)d_out;

    // workspace layout (~28.7 MB; all regions fully written before read each call)
    char* p = (char*)d_ws;
    unsigned short* WT0 = (unsigned short*)p; p += (size_t)6 * WSTRIDE * 2;
    unsigned short* WTe = (unsigned short*)p; p += (size_t)3 * WESTRIDE * 2;
    unsigned short* fb  = (unsigned short*)p; p += (size_t)NNODES * 128 * 2;
    int* gx   = (int*)p;                      p += (size_t)3 * RPM * 4;
    int* eid1 = (int*)p;                      p += (size_t)3 * 16384 * 4;
    unsigned short* fout = (unsigned short*)p; p += (size_t)3 * RPM * 128 * 2;
    float* femb = (float*)p;                   p += (size_t)3 * B * 128 * 4;

    convsamp_k<<<TOT_TASKS / 256, 256, 0, stream>>>(feats, Ws, Wn, We, ids, adjn, adje,
                                                    fb, WT0, WTe, gx, eid1);
    aggfeat_k<<<dim3(RPM / 16, 3), 256, 0, stream>>>(fb, edge_emb, adjn, adje, gx, eid1,
                                                     WT0, fout);
    edgeagg_k<<<dim3(256, 3), 256, 0, stream>>>(fout, edge_emb, eid1, WTe, WT0, femb);
    fin_k<<<32, 256, 0, stream>>>(femb, attn, fcw, fcb, out);
}